// Round 7
// baseline (416.974 us; speedup 1.0000x reference)
//
#include <hip/hip_runtime.h>
#include <hip/hip_bf16.h>
#include <stdint.h>

typedef __bf16 bf16x8 __attribute__((ext_vector_type(8)));
typedef float f32x4 __attribute__((ext_vector_type(4)));

#define LOG2E 1.4426950408889634f
#define AS1 __attribute__((address_space(1)))
#define AS3 __attribute__((address_space(3)))

// Operand layout ("tile-frag order", 256-row panels): panel = 256 rows,
// stored as [k-tile t (32 k)][frag f 0..15 (16 rows)][lane l 0..63] x 16B,
// chunk (f,l) holds row f*16+(l&15), k = t*32 + (l>>4)*8.
//  -> GEMM staging is perfectly sequential (base + tid*16, 8KB/wave-instr)
//  -> LDS fragment reads are contiguous 1KB wave accesses (conflict-free)
//  -> matches mfma_f32_16x16x32_bf16 A/B fragment layout (verified r6)

// ---------------- prep: build indices from batch_sizes ----------------
__global__ void prep_kernel(const int* __restrict__ bs, int T,
                            const int* __restrict__ sentences,
                            int* __restrict__ hdr, float* __restrict__ fhdr,
                            int* __restrict__ row_ctx, int* __restrict__ row_tok) {
    __shared__ int off[1025];
    if (threadIdx.x == 0) {
        int acc = 0; off[0] = 0;
        for (int t = 0; t < T; ++t) { acc += bs[t]; off[t + 1] = acc; }
    }
    __syncthreads();
    const int total = off[T];
    const int Nf = total - off[1];
    const int Nb = total - off[2];
    for (int t = 1; t < T; ++t) {
        int start = off[t] - off[1];
        int cnt = off[t + 1] - off[t];
        for (int p = threadIdx.x; p < cnt; p += blockDim.x) {
            row_ctx[start + p] = off[t - 1] + p;
            row_tok[start + p] = sentences[off[t] + p];
        }
    }
    for (int i = 1; i < T - 1; ++i) {
        int start = Nf + off[i + 1] - off[2];
        int cnt = off[i + 2] - off[i + 1];
        for (int p = threadIdx.x; p < cnt; p += blockDim.x) {
            row_ctx[start + p] = off[i + 1] + p;
            row_tok[start + p] = sentences[off[i] + p];
        }
    }
    if (threadIdx.x == 0) {
        hdr[0] = Nf + Nb;
        hdr[1] = Nf;
        int bs0 = off[1];
        int bsl = off[T] - off[T - 1];
        fhdr[0] = (float)(2 * total - bs0 - bsl);
    }
}

__device__ __forceinline__ int4 cvt8(float4 v0, float4 v1) {
    union { __hip_bfloat16 h[8]; int4 i4; } u;
    u.h[0] = __float2bfloat16(v0.x); u.h[1] = __float2bfloat16(v0.y);
    u.h[2] = __float2bfloat16(v0.z); u.h[3] = __float2bfloat16(v0.w);
    u.h[4] = __float2bfloat16(v1.x); u.h[5] = __float2bfloat16(v1.y);
    u.h[6] = __float2bfloat16(v1.z); u.h[7] = __float2bfloat16(v1.w);
    return u.i4;
}

// ---------------- W f32 -> bf16, 256-row tile-frag panels ----------------
// grid: (V/256)*16 blocks x 512 threads; block (p = bx>>4, f = bx&15)
__global__ void wconv_kernel(const float* __restrict__ W,
                             __hip_bfloat16* __restrict__ Wb, int K) {
    const int p = blockIdx.x >> 4, f = blockIdx.x & 15;
    char* panel = (char*)Wb + (size_t)p * ((size_t)K << 9);
    const int nch = 2 * K;   // (K/32 tiles) * 64 lanes
    for (int c = threadIdx.x; c < nch; c += 512) {
        const int t = c >> 6, l = c & 63;
        const int row = p * 256 + f * 16 + (l & 15);
        const int k = t * 32 + ((l >> 4) << 3);
        const float4* src = (const float4*)(W + (size_t)row * K + k);
        *(int4*)(panel + (size_t)t * 16384 + f * 1024 + l * 16) = cvt8(src[0], src[1]);
    }
}

// ---------------- gather ctx rows -> bf16 256-row tile-frag panels, zero S --
// grid: (Mcap/256)*16 blocks x 512 threads; block (p = bx>>4, f = bx&15)
__global__ void gather_kernel(const float* __restrict__ hs,
                              const int* __restrict__ row_ctx,
                              const int* __restrict__ hdr,
                              __hip_bfloat16* __restrict__ Hc,
                              float* __restrict__ S, int D2, int K) {
    const int p = blockIdx.x >> 4, f = blockIdx.x & 15;
    const int M = hdr[0], Nf = hdr[1];
    if (threadIdx.x < 16) S[p * 256 + f * 16 + threadIdx.x] = 0.f;
    char* panel = (char*)Hc + (size_t)p * ((size_t)K << 9);
    const int nch = 2 * K;
    for (int c = threadIdx.x; c < nch; c += 512) {
        const int t = c >> 6, l = c & 63;
        const int row = p * 256 + f * 16 + (l & 15);
        char* d = panel + (size_t)t * 16384 + f * 1024 + l * 16;
        if (row >= M) {
            int4 z; z.x = z.y = z.z = z.w = 0;
            *(int4*)d = z;
        } else {
            const int ctx = row_ctx[row];
            const int k = t * 32 + ((l >> 4) << 3);
            const float4* src = (const float4*)(hs + (size_t)ctx * D2 + (row < Nf ? 0 : K) + k);
            *(int4*)d = cvt8(src[0], src[1]);
        }
    }
}

// ---------------- main 256x256 / 8-wave / 8-phase-style GEMM + sum-exp -------
// 4-deep LDS pipeline over BK=32 sub-steps; counted vmcnt gate (8) once per
// sub-step; 2 phases of 16 MFMA each; setprio around clusters (T5).
// Staging into buf[(t+3)&3] = buf[(t-1)&3] is safe after phase-1 barrier:
// every wave's reads of that buffer were register-consumed (in-order wave)
// before it reached the barrier.
__global__ __launch_bounds__(512, 2)
void gemm_lse_256(const __hip_bfloat16* __restrict__ A,
                  const __hip_bfloat16* __restrict__ B,
                  const float* __restrict__ fb,
                  const float* __restrict__ bb,
                  float* __restrict__ S,
                  const int* __restrict__ hdr, int K, int MT) {
    const int M = hdr[0], Nf = hdr[1];

    // XCD-aware bijective swizzle (m204), bm-fastest (r2: FETCH -48%).
    const int nwg = gridDim.x, orig = blockIdx.x;
    const int q = nwg >> 3, rr = nwg & 7;
    const int xcd = orig & 7, i8 = orig >> 3;
    const int wgid = (xcd < rr ? xcd * (q + 1) : rr * (q + 1) + (xcd - rr) * q) + i8;
    const int bm = wgid % MT, bn = wgid / MT;
    if (bm * 256 >= M) return;

    __shared__ __align__(16) char lds[4][32768];   // [buf][A 16KB | B 16KB]

    const int tid = threadIdx.x, lane = tid & 63, wid = tid >> 6;
    const int wm = wid >> 2, wn = wid & 3;          // 2M x 4N, 128x64 per wave

    f32x4 acc[8][4];
#pragma unroll
    for (int i = 0; i < 8; ++i)
#pragma unroll
        for (int j = 0; j < 4; ++j) acc[i][j] = (f32x4)0.f;

    const char* Ap = (const char*)A + (size_t)bm * ((size_t)K << 9);
    const char* Bp = (const char*)B + (size_t)bn * ((size_t)K << 9);
    const int sd = tid << 4;
    const int ao = ((wm * 8) << 10) + (lane << 4);          // + mf*1024
    const int bo = 16384 + ((wn * 4) << 10) + (lane << 4);  // + nf*1024

#define GLDS(src, dst) __builtin_amdgcn_global_load_lds(                      \
        (const AS1 uint32_t*)(src), (AS3 uint32_t*)(dst), 16, 0, 0)
#define STAGE_A(bi, t) do {                                                   \
    GLDS(Ap + (size_t)(t) * 16384 + sd,        lds[bi] + sd);                 \
    GLDS(Ap + (size_t)(t) * 16384 + 8192 + sd, lds[bi] + 8192 + sd);          \
} while (0)
#define STAGE_B(bi, t) do {                                                   \
    GLDS(Bp + (size_t)(t) * 16384 + sd,        lds[bi] + 16384 + sd);         \
    GLDS(Bp + (size_t)(t) * 16384 + 8192 + sd, lds[bi] + 24576 + sd);         \
} while (0)
#define CL(MLO) do {                                                          \
    __builtin_amdgcn_s_setprio(1);                                            \
    _Pragma("unroll")                                                         \
    for (int _i = 0; _i < 4; ++_i)                                            \
        _Pragma("unroll")                                                     \
        for (int _n = 0; _n < 4; ++_n)                                        \
            acc[(MLO) + _i][_n] = __builtin_amdgcn_mfma_f32_16x16x32_bf16(    \
                a[(MLO) + _i], b[_n], acc[(MLO) + _i][_n], 0, 0, 0);          \
    __builtin_amdgcn_s_setprio(0);                                            \
} while (0)
#define BARR() do {                                                           \
    __builtin_amdgcn_sched_barrier(0);                                        \
    __builtin_amdgcn_s_barrier();                                             \
    __builtin_amdgcn_sched_barrier(0);                                        \
} while (0)
#define GATE(n) asm volatile("s_waitcnt vmcnt(" #n ")" ::: "memory")

    const int NT = K >> 5;   // BK=32 sub-steps (K=1024 -> 32); requires NT>=4

    // prologue: 3 sub-steps in flight (12 loads; oldest 4 = sub-step 0)
    STAGE_A(0, 0); STAGE_B(0, 0);
    STAGE_A(1, 1); STAGE_B(1, 1);
    STAGE_A(2, 2); STAGE_B(2, 2);

    for (int t = 0; t < NT - 3; ++t) {
        const char* bp = lds[t & 3];
        const int nb = (t + 3) & 3;
        bf16x8 a[8], b[4];
        // phase 1: gate(t landed for all waves), read frags, stage A(t+3)
        GATE(8); BARR();
#pragma unroll
        for (int mf = 0; mf < 4; ++mf) a[mf] = *(const bf16x8*)(bp + ao + (mf << 10));
#pragma unroll
        for (int nf = 0; nf < 4; ++nf) b[nf] = *(const bf16x8*)(bp + bo + (nf << 10));
        STAGE_A(nb, t + 3);
        CL(0);
        // phase 2: read remaining A frags, stage B(t+3)
        BARR();
#pragma unroll
        for (int mf = 4; mf < 8; ++mf) a[mf] = *(const bf16x8*)(bp + ao + (mf << 10));
        STAGE_B(nb, t + 3);
        CL(4);
    }
    // tail: 3 sub-steps, gates 8/4/0, no staging
#define TAILSTEP(T_, GN) do {                                                 \
    const char* bp = lds[(T_) & 3];                                           \
    bf16x8 a[8], b[4];                                                        \
    GATE(GN); BARR();                                                         \
    _Pragma("unroll")                                                         \
    for (int mf = 0; mf < 4; ++mf) a[mf] = *(const bf16x8*)(bp + ao + (mf << 10)); \
    _Pragma("unroll")                                                         \
    for (int nf = 0; nf < 4; ++nf) b[nf] = *(const bf16x8*)(bp + bo + (nf << 10)); \
    CL(0);                                                                    \
    BARR();                                                                   \
    _Pragma("unroll")                                                         \
    for (int mf = 4; mf < 8; ++mf) a[mf] = *(const bf16x8*)(bp + ao + (mf << 10)); \
    CL(4);                                                                    \
} while (0)
    TAILSTEP(NT - 3, 8);
    TAILSTEP(NT - 2, 4);
    TAILSTEP(NT - 1, 0);

    // epilogue: bias + exp + 64-col row partials + atomic (verified r1-r6)
    float fbv[4], bbv[4];
#pragma unroll
    for (int nf = 0; nf < 4; ++nf) {
        const int v = bn * 256 + wn * 64 + nf * 16 + (lane & 15);
        fbv[nf] = fb[v]; bbv[nf] = bb[v];
    }
#pragma unroll
    for (int mf = 0; mf < 8; ++mf) {
#pragma unroll
        for (int j = 0; j < 4; ++j) {
            const int m = bm * 256 + wm * 128 + mf * 16 + ((lane >> 4) << 2) + j;
            if (m >= M) continue;   // uniform within each 16-lane shuffle group
            const bool isf = m < Nf;
            float ps = 0.f;
#pragma unroll
            for (int nf = 0; nf < 4; ++nf) {
                const float logit = acc[mf][nf][j] + (isf ? fbv[nf] : bbv[nf]);
                ps += exp2f(logit * LOG2E);
            }
#pragma unroll
            for (int s = 1; s < 16; s <<= 1) ps += __shfl_xor(ps, s);
            if ((lane & 15) == 0) atomicAdd(&S[m], ps);
        }
    }
#undef GLDS
#undef STAGE_A
#undef STAGE_B
#undef CL
#undef BARR
#undef GATE
#undef TAILSTEP
}

// ---------------- fallback (ws too small for Wb): simple sync 256^2 ----------
__global__ __launch_bounds__(512)
void gemm_lse_fb(const __hip_bfloat16* __restrict__ A, const float* __restrict__ Bf,
                 const float* __restrict__ fb, const float* __restrict__ bb,
                 float* __restrict__ S, const int* __restrict__ hdr, int K, int MT) {
    const int M = hdr[0], Nf = hdr[1];
    const int bm = blockIdx.x % MT, bn = blockIdx.x / MT;
    if (bm * 256 >= M) return;
    __shared__ __align__(16) char lds[32768];
    const int tid = threadIdx.x, lane = tid & 63, wid = tid >> 6;
    const int wm = wid >> 2, wn = wid & 3;
    f32x4 acc[8][4];
#pragma unroll
    for (int i = 0; i < 8; ++i)
#pragma unroll
        for (int j = 0; j < 4; ++j) acc[i][j] = (f32x4)0.f;
    const char* Ap = (const char*)A + (size_t)bm * ((size_t)K << 9);
    const int sd = tid << 4;
    const int ao = ((wm * 8) << 10) + (lane << 4);
    const int bo = 16384 + ((wn * 4) << 10) + (lane << 4);
    const int NT = K >> 5;
    for (int t = 0; t < NT; ++t) {
        __syncthreads();
        __builtin_amdgcn_global_load_lds((const AS1 uint32_t*)(Ap + (size_t)t * 16384 + sd),
                                         (AS3 uint32_t*)(lds + sd), 16, 0, 0);
        __builtin_amdgcn_global_load_lds((const AS1 uint32_t*)(Ap + (size_t)t * 16384 + 8192 + sd),
                                         (AS3 uint32_t*)(lds + 8192 + sd), 16, 0, 0);
#pragma unroll
        for (int j = 0; j < 2; ++j) {
            const int c = j * 512 + tid;
            const int f = c >> 6, l = c & 63;
            const int row = bn * 256 + f * 16 + (l & 15);
            const int k = t * 32 + ((l >> 4) << 3);
            const float4* src = (const float4*)(Bf + (size_t)row * K + k);
            *(int4*)(lds + 16384 + c * 16) = cvt8(src[0], src[1]);
        }
        __syncthreads();
        bf16x8 a[8], b[4];
#pragma unroll
        for (int mf = 0; mf < 8; ++mf) a[mf] = *(const bf16x8*)(lds + ao + (mf << 10));
#pragma unroll
        for (int nf = 0; nf < 4; ++nf) b[nf] = *(const bf16x8*)(lds + bo + (nf << 10));
#pragma unroll
        for (int mf = 0; mf < 8; ++mf)
#pragma unroll
            for (int nf = 0; nf < 4; ++nf)
                acc[mf][nf] = __builtin_amdgcn_mfma_f32_16x16x32_bf16(a[mf], b[nf], acc[mf][nf], 0, 0, 0);
    }
    float fbv[4], bbv[4];
#pragma unroll
    for (int nf = 0; nf < 4; ++nf) {
        const int v = bn * 256 + wn * 64 + nf * 16 + (lane & 15);
        fbv[nf] = fb[v]; bbv[nf] = bb[v];
    }
#pragma unroll
    for (int mf = 0; mf < 8; ++mf) {
#pragma unroll
        for (int j = 0; j < 4; ++j) {
            const int m = bm * 256 + wm * 128 + mf * 16 + ((lane >> 4) << 2) + j;
            if (m >= M) continue;
            const bool isf = m < Nf;
            float ps = 0.f;
#pragma unroll
            for (int nf = 0; nf < 4; ++nf) {
                const float logit = acc[mf][nf][j] + (isf ? fbv[nf] : bbv[nf]);
                ps += exp2f(logit * LOG2E);
            }
#pragma unroll
            for (int s = 1; s < 16; s <<= 1) ps += __shfl_xor(ps, s);
            if ((lane & 15) == 0) atomicAdd(&S[m], ps);
        }
    }
}

// ---------------- gold logits (exact f32) ----------------
__global__ void gold_kernel(const float* __restrict__ hs,
                            const float* __restrict__ W,
                            const float* __restrict__ fb,
                            const float* __restrict__ bb,
                            const int* __restrict__ row_ctx,
                            const int* __restrict__ row_tok,
                            const int* __restrict__ hdr,
                            float* __restrict__ goldv, int D2, int D) {
    const int m = blockIdx.x;
    const int M = hdr[0];
    if (m >= M) return;
    const int Nf = hdr[1];
    const int ctx = row_ctx[m], tok = row_tok[m];
    const float4* h = (const float4*)(hs + (size_t)ctx * D2 + (m < Nf ? 0 : D));
    const float4* w = (const float4*)(W + (size_t)tok * D);
    float s = 0.f;
    for (int i = threadIdx.x; i < D / 4; i += blockDim.x) {
        float4 a = h[i], b = w[i];
        s += a.x * b.x + a.y * b.y + a.z * b.z + a.w * b.w;
    }
#pragma unroll
    for (int d = 1; d < 64; d <<= 1) s += __shfl_xor(s, d);
    __shared__ float wsum[4];
    const int wid = threadIdx.x >> 6, lane = threadIdx.x & 63;
    if (lane == 0) wsum[wid] = s;
    __syncthreads();
    if (threadIdx.x == 0) {
        float tot = wsum[0] + wsum[1] + wsum[2] + wsum[3];
        tot += (m < Nf ? fb[tok] : bb[tok]);
        goldv[m] = tot;
    }
}

// ---------------- final reduce ----------------
__global__ void final_kernel(const float* __restrict__ S,
                             const float* __restrict__ goldv,
                             const int* __restrict__ hdr,
                             const float* __restrict__ fhdr,
                             float* __restrict__ out) {
    const int M = hdr[0];
    float s = 0.f;
    for (int m = threadIdx.x; m < M; m += blockDim.x)
        s += logf(S[m]) - goldv[m];
#pragma unroll
    for (int d = 1; d < 64; d <<= 1) s += __shfl_xor(s, d);
    __shared__ float wsum[4];
    const int wid = threadIdx.x >> 6, lane = threadIdx.x & 63;
    if (lane == 0) wsum[wid] = s;
    __syncthreads();
    if (threadIdx.x == 0)
        out[0] = (wsum[0] + wsum[1] + wsum[2] + wsum[3]) / fhdr[0];
}

extern "C" void kernel_launch(void* const* d_in, const int* in_sizes, int n_in,
                              void* d_out, int out_size, void* d_ws, size_t ws_size,
                              hipStream_t stream) {
    const float* hs  = (const float*)d_in[0];
    const float* W   = (const float*)d_in[1];
    const float* fb  = (const float*)d_in[2];
    const float* bb  = (const float*)d_in[3];
    const int* sent  = (const int*)d_in[4];
    const int* bs    = (const int*)d_in[5];
    const int total  = in_sizes[4];
    const int T      = in_sizes[5];
    const int V      = in_sizes[2];
    const int D      = in_sizes[1] / V;
    const int D2     = in_sizes[0] / total;
    const int Mcap   = ((2 * total) + 255) & ~255;   // 256-aligned upper bound
    const int MT     = Mcap / 256;
    const int NN     = V / 256;

    char* p = (char*)d_ws;
    int*   hdr     = (int*)p;            p += 256;
    float* fhdr    = (float*)p;          p += 256;
    int*   row_ctx = (int*)p;            p += (size_t)Mcap * 4;
    int*   row_tok = (int*)p;            p += (size_t)Mcap * 4;
    float* S       = (float*)p;          p += (size_t)Mcap * 4;
    float* goldv   = (float*)p;          p += (size_t)Mcap * 4;
    __hip_bfloat16* Hc = (__hip_bfloat16*)p; p += (size_t)Mcap * D * 2;
    __hip_bfloat16* Wb = (__hip_bfloat16*)p;
    const size_t need_wb = (size_t)(p - (char*)d_ws) + (size_t)V * D * 2;

    prep_kernel<<<1, 256, 0, stream>>>(bs, T, sent, hdr, fhdr, row_ctx, row_tok);
    gather_kernel<<<(Mcap / 256) * 16, 512, 0, stream>>>(hs, row_ctx, hdr, Hc, S, D2, D);

    if (ws_size >= need_wb) {
        wconv_kernel<<<(V / 256) * 16, 512, 0, stream>>>(W, Wb, D);
        gemm_lse_256<<<NN * MT, 512, 0, stream>>>(Hc, Wb, fb, bb, S, hdr, D, MT);
    } else {
        gemm_lse_fb<<<NN * MT, 512, 0, stream>>>(Hc, W, fb, bb, S, hdr, D, MT);
    }

    gold_kernel<<<Mcap, 256, 0, stream>>>(hs, W, fb, bb, row_ctx, row_tok, hdr, goldv, D2, D);
    final_kernel<<<1, 256, 0, stream>>>(S, goldv, hdr, fhdr, (float*)d_out);
}

// Round 8
// 278.939 us; speedup vs baseline: 1.4949x; 1.4949x over previous
//
#include <hip/hip_runtime.h>
#include <hip/hip_bf16.h>
#include <stdint.h>

typedef float f32x4 __attribute__((ext_vector_type(4)));

#define LOG2E 1.4426950408889634f
#define WSCALE 16.0f
#define AS1 __attribute__((address_space(1)))
#define AS3 __attribute__((address_space(3)))

// fp8 operand layout ("tile-frag order"): a row-panel of R rows (R=128 for A,
// 256 for B) stored as [k-tile t (32 k)][frag f (16 rows)][lane l 0..63] x 8B;
// chunk (f,l) holds row f*16+(l&15), k = t*32 + (l>>4)*8 — exactly the
// mfma_f32_16x16x32_fp8_fp8 A/B fragment (8 fp8/lane). Staging is a
// byte-identical sequential copy (base + tid*16); LDS fragment reads are
// contiguous 512B wave accesses (conflict-free). W is scaled x16 before
// quantization (std 0.031 -> 0.5, avoiding e4m3 subnormals); the epilogue
// multiplies logits by 1/16.

// ---------------- f32 -> OCP e4m3 (RNE, clamp to 448) ----------------
__device__ __forceinline__ uint32_t f32_to_e4m3(float x) {
    uint32_t ux = __float_as_uint(x);
    uint32_t s = (ux >> 24) & 0x80u;
    float a = __uint_as_float(ux & 0x7FFFFFFFu);
    if (a >= 448.0f) return s | 0x7Eu;
    int e = (int)((ux >> 23) & 0xFFu) - 127;
    if (e < -6) {                          // subnormal: steps of 2^-9
        int n = __float2int_rn(a * 512.0f);  // 0..8 (8 == 2^-6 == 0x08, still valid)
        return s | (uint32_t)n;
    }
    uint32_t m = ux & 0x7FFFFFu;
    uint32_t r = (m + 0x7FFFFu + ((m >> 20) & 1u)) >> 20;  // RNE to 3 bits, 0..8
    if (r == 8u) { r = 0u; e += 1; }
    if (e > 8 || (e == 8 && r == 7u)) return s | 0x7Eu;    // clamp (0x7F is NaN)
    return s | ((uint32_t)(e + 7) << 3) | r;
}

__device__ __forceinline__ uint2 cvt8_fp8(float4 v0, float4 v1, float sc) {
    uint32_t lo = f32_to_e4m3(v0.x * sc) | (f32_to_e4m3(v0.y * sc) << 8) |
                  (f32_to_e4m3(v0.z * sc) << 16) | (f32_to_e4m3(v0.w * sc) << 24);
    uint32_t hi = f32_to_e4m3(v1.x * sc) | (f32_to_e4m3(v1.y * sc) << 8) |
                  (f32_to_e4m3(v1.z * sc) << 16) | (f32_to_e4m3(v1.w * sc) << 24);
    return make_uint2(lo, hi);
}

// ---------------- prep: build indices from batch_sizes ----------------
__global__ void prep_kernel(const int* __restrict__ bs, int T,
                            const int* __restrict__ sentences,
                            int* __restrict__ hdr, float* __restrict__ fhdr,
                            int* __restrict__ row_ctx, int* __restrict__ row_tok) {
    __shared__ int off[1025];
    if (threadIdx.x == 0) {
        int acc = 0; off[0] = 0;
        for (int t = 0; t < T; ++t) { acc += bs[t]; off[t + 1] = acc; }
    }
    __syncthreads();
    const int total = off[T];
    const int Nf = total - off[1];
    const int Nb = total - off[2];
    for (int t = 1; t < T; ++t) {
        int start = off[t] - off[1];
        int cnt = off[t + 1] - off[t];
        for (int p = threadIdx.x; p < cnt; p += blockDim.x) {
            row_ctx[start + p] = off[t - 1] + p;
            row_tok[start + p] = sentences[off[t] + p];
        }
    }
    for (int i = 1; i < T - 1; ++i) {
        int start = Nf + off[i + 1] - off[2];
        int cnt = off[i + 2] - off[i + 1];
        for (int p = threadIdx.x; p < cnt; p += blockDim.x) {
            row_ctx[start + p] = off[i + 1] + p;
            row_tok[start + p] = sentences[off[i] + p];
        }
    }
    if (threadIdx.x == 0) {
        hdr[0] = Nf + Nb;
        hdr[1] = Nf;
        int bs0 = off[1];
        int bsl = off[T] - off[T - 1];
        fhdr[0] = (float)(2 * total - bs0 - bsl);
    }
}

// ---------------- W f32 -> fp8 (x16), 256-row tile-frag panels ----------------
// grid: (V/256)*16 blocks x 512 threads; block (p = bx>>4, f = bx&15)
__global__ void wconv_kernel(const float* __restrict__ W,
                             uint8_t* __restrict__ Wb, int K) {
    const int p = blockIdx.x >> 4, f = blockIdx.x & 15;
    char* panel = (char*)Wb + (size_t)p * ((size_t)K << 8);   // 256 rows * K bytes
    const int nch = 2 * K;   // (K/32) * 64
    for (int c = threadIdx.x; c < nch; c += 512) {
        const int t = c >> 6, l = c & 63;
        const int row = p * 256 + f * 16 + (l & 15);
        const int k = t * 32 + ((l >> 4) << 3);
        const float4* src = (const float4*)(W + (size_t)row * K + k);
        *(uint2*)(panel + (size_t)t * 8192 + f * 512 + l * 8) = cvt8_fp8(src[0], src[1], WSCALE);
    }
}

// ---------------- gather ctx rows -> fp8 128-row tile-frag panels, zero S ----
// grid: (Mcap/128)*8 blocks x 512 threads; block (p = bx>>3, f = bx&7)
__global__ void gather_kernel(const float* __restrict__ hs,
                              const int* __restrict__ row_ctx,
                              const int* __restrict__ hdr,
                              uint8_t* __restrict__ Hc,
                              float* __restrict__ S, int D2, int K) {
    const int p = blockIdx.x >> 3, f = blockIdx.x & 7;
    const int M = hdr[0], Nf = hdr[1];
    if (f == 0 && threadIdx.x < 128) S[p * 128 + threadIdx.x] = 0.f;
    char* panel = (char*)Hc + (size_t)p * ((size_t)K << 7);   // 128 rows * K bytes
    const int nch = 2 * K;
    for (int c = threadIdx.x; c < nch; c += 512) {
        const int t = c >> 6, l = c & 63;
        const int row = p * 128 + f * 16 + (l & 15);
        char* d = panel + (size_t)t * 4096 + f * 512 + l * 8;
        if (row >= M) {
            *(uint2*)d = make_uint2(0u, 0u);
        } else {
            const int ctx = row_ctx[row];
            const int k = t * 32 + ((l >> 4) << 3);
            const float4* src = (const float4*)(hs + (size_t)ctx * D2 + (row < Nf ? 0 : K) + k);
            *(uint2*)d = cvt8_fp8(src[0], src[1], 1.0f);
        }
    }
}

// ---------------- main 128x256 / BK=64 / 8-wave fp8 GEMM + sum-exp ----------
// r6's proven schedule (STAGE ahead -> vmcnt(3) -> bar -> COMPUTE -> bar),
// 2 blocks/CU, sequential staging; fp8 halves LDS traffic, BK=64 halves gates.
__global__ __launch_bounds__(512, 4)
void gemm_lse(const uint8_t* __restrict__ A,
              const uint8_t* __restrict__ B,
              const float* __restrict__ fb,
              const float* __restrict__ bb,
              float* __restrict__ S,
              const int* __restrict__ hdr, int K, int MT) {
    const int M = hdr[0], Nf = hdr[1];

    // XCD-aware bijective swizzle (m204), bm-fastest (verified r2/r6).
    const int nwg = gridDim.x, orig = blockIdx.x;
    const int q = nwg >> 3, rr = nwg & 7;
    const int xcd = orig & 7, i8 = orig >> 3;
    const int wgid = (xcd < rr ? xcd * (q + 1) : rr * (q + 1) + (xcd - rr) * q) + i8;
    const int bm = wgid % MT, bn = wgid / MT;
    if (bm * 128 >= M) return;

    __shared__ __align__(16) char lA[2][8192];     // BK=64 of A (128 rows)
    __shared__ __align__(16) char lB[2][16384];    // BK=64 of B (256 rows)

    const int tid = threadIdx.x, lane = tid & 63, wid = tid >> 6;
    const int wm = wid >> 2, wn = wid & 3;     // 2M x 4N waves, each 64x64 out

    f32x4 acc[4][4];
#pragma unroll
    for (int i = 0; i < 4; ++i)
#pragma unroll
        for (int j = 0; j < 4; ++j) acc[i][j] = (f32x4)0.f;

    const char* Ap = (const char*)A + (size_t)bm * ((size_t)K << 7);
    const char* Bp = (const char*)B + (size_t)bn * ((size_t)K << 8);
    const int sd = tid << 4;
    const int ao = ((wm * 4) << 9) + (lane << 3);   // + mf*512 + kk*4096
    const int bo = ((wn * 4) << 9) + (lane << 3);   // + nf*512 + kk*8192

#define GLDS(src, dst) __builtin_amdgcn_global_load_lds(                      \
        (const AS1 uint32_t*)(src), (AS3 uint32_t*)(dst), 16, 0, 0)

#define STAGE(buf, s) do {                                                    \
    GLDS(Ap + ((size_t)(s) << 13) + sd,        lA[buf] + sd);                 \
    GLDS(Bp + ((size_t)(s) << 14) + sd,        lB[buf] + sd);                 \
    GLDS(Bp + ((size_t)(s) << 14) + 8192 + sd, lB[buf] + 8192 + sd);          \
} while (0)

#define COMPUTE(buf) do {                                                     \
    long a[8], b[8];                                                          \
    _Pragma("unroll")                                                         \
    for (int kk = 0; kk < 2; ++kk) {                                          \
        _Pragma("unroll")                                                     \
        for (int mf = 0; mf < 4; ++mf)                                        \
            a[kk * 4 + mf] = *(const long*)(lA[buf] + kk * 4096 + ao + (mf << 9)); \
        _Pragma("unroll")                                                     \
        for (int nf = 0; nf < 4; ++nf)                                        \
            b[kk * 4 + nf] = *(const long*)(lB[buf] + kk * 8192 + bo + (nf << 9)); \
    }                                                                         \
    __builtin_amdgcn_s_setprio(1);                                            \
    _Pragma("unroll")                                                         \
    for (int kk = 0; kk < 2; ++kk)                                            \
        _Pragma("unroll")                                                     \
        for (int mf = 0; mf < 4; ++mf)                                        \
            _Pragma("unroll")                                                 \
            for (int nf = 0; nf < 4; ++nf)                                    \
                acc[mf][nf] = __builtin_amdgcn_mfma_f32_16x16x32_fp8_fp8(     \
                    a[kk * 4 + mf], b[kk * 4 + nf], acc[mf][nf], 0, 0, 0);    \
    __builtin_amdgcn_s_setprio(0);                                            \
} while (0)

#define BAR() do { __builtin_amdgcn_s_barrier(); __builtin_amdgcn_sched_barrier(0); } while (0)

    const int NT = K >> 6;   // BK=64 steps (K=1024 -> 16)

    STAGE(0, 0);
    for (int t = 0; t < NT - 1; ++t) {
        STAGE((t + 1) & 1, t + 1);                        // 3 loads in flight
        asm volatile("s_waitcnt vmcnt(3)" ::: "memory");  // tile t landed
        BAR();
        COMPUTE(t & 1);
        BAR();   // all waves done reading buf[t&1] before t+1 overwrites it
    }
    asm volatile("s_waitcnt vmcnt(0)" ::: "memory");
    BAR();
    COMPUTE((NT - 1) & 1);

    // epilogue: logit = acc/WSCALE + bias; ps = sum exp2(logit*LOG2E)
    float fbv[4], bbv[4];
#pragma unroll
    for (int nf = 0; nf < 4; ++nf) {
        const int v = bn * 256 + wn * 64 + nf * 16 + (lane & 15);
        fbv[nf] = fb[v] * LOG2E; bbv[nf] = bb[v] * LOG2E;
    }
    const float k1 = LOG2E / WSCALE;
#pragma unroll
    for (int mf = 0; mf < 4; ++mf) {
#pragma unroll
        for (int j = 0; j < 4; ++j) {
            const int m = bm * 128 + wm * 64 + mf * 16 + ((lane >> 4) << 2) + j;
            if (m >= M) continue;   // uniform within each 16-lane shuffle group
            const bool isf = m < Nf;
            float ps = 0.f;
#pragma unroll
            for (int nf = 0; nf < 4; ++nf)
                ps += exp2f(fmaf(acc[mf][nf][j], k1, isf ? fbv[nf] : bbv[nf]));
#pragma unroll
            for (int s = 1; s < 16; s <<= 1) ps += __shfl_xor(ps, s);
            if ((lane & 15) == 0) atomicAdd(&S[m], ps);
        }
    }
#undef GLDS
#undef STAGE
#undef COMPUTE
#undef BAR
}

// ---------------- fallback (ws too small): naive exact f32 sum-exp ----------
__global__ void lse_naive(const float* __restrict__ hs,
                          const float* __restrict__ W,
                          const float* __restrict__ fb,
                          const float* __restrict__ bb,
                          const int* __restrict__ row_ctx,
                          const int* __restrict__ hdr,
                          float* __restrict__ S, int D2, int D, int V) {
    const int m = blockIdx.x;
    const int M = hdr[0], Nf = hdr[1];
    if (m >= M) return;
    __shared__ float hrow[2048];
    const int ctx = row_ctx[m];
    const float* h = hs + (size_t)ctx * D2 + (m < Nf ? 0 : D);
    for (int i = threadIdx.x; i < D; i += blockDim.x) hrow[i] = h[i];
    __syncthreads();
    const float* bias = (m < Nf) ? fb : bb;
    float ps = 0.f;
    for (int v = threadIdx.x; v < V; v += blockDim.x) {
        const float* w = W + (size_t)v * D;
        float dot = 0.f;
        for (int k = 0; k < D; ++k) dot = fmaf(hrow[k], w[k], dot);
        ps += exp2f((dot + bias[v]) * LOG2E);
    }
#pragma unroll
    for (int d = 1; d < 64; d <<= 1) ps += __shfl_xor(ps, d);
    __shared__ float wsum[4];
    const int wid = threadIdx.x >> 6, lane = threadIdx.x & 63;
    if (lane == 0) wsum[wid] = ps;
    __syncthreads();
    if (threadIdx.x == 0) S[m] = wsum[0] + wsum[1] + wsum[2] + wsum[3];
}

// ---------------- gold logits (exact f32) ----------------
__global__ void gold_kernel(const float* __restrict__ hs,
                            const float* __restrict__ W,
                            const float* __restrict__ fb,
                            const float* __restrict__ bb,
                            const int* __restrict__ row_ctx,
                            const int* __restrict__ row_tok,
                            const int* __restrict__ hdr,
                            float* __restrict__ goldv, int D2, int D) {
    const int m = blockIdx.x;
    const int M = hdr[0];
    if (m >= M) return;
    const int Nf = hdr[1];
    const int ctx = row_ctx[m], tok = row_tok[m];
    const float4* h = (const float4*)(hs + (size_t)ctx * D2 + (m < Nf ? 0 : D));
    const float4* w = (const float4*)(W + (size_t)tok * D);
    float s = 0.f;
    for (int i = threadIdx.x; i < D / 4; i += blockDim.x) {
        float4 a = h[i], b = w[i];
        s += a.x * b.x + a.y * b.y + a.z * b.z + a.w * b.w;
    }
#pragma unroll
    for (int d = 1; d < 64; d <<= 1) s += __shfl_xor(s, d);
    __shared__ float wsum[4];
    const int wid = threadIdx.x >> 6, lane = threadIdx.x & 63;
    if (lane == 0) wsum[wid] = s;
    __syncthreads();
    if (threadIdx.x == 0) {
        float tot = wsum[0] + wsum[1] + wsum[2] + wsum[3];
        tot += (m < Nf ? fb[tok] : bb[tok]);
        goldv[m] = tot;
    }
}

// ---------------- final reduce ----------------
__global__ void final_kernel(const float* __restrict__ S,
                             const float* __restrict__ goldv,
                             const int* __restrict__ hdr,
                             const float* __restrict__ fhdr,
                             float* __restrict__ out) {
    const int M = hdr[0];
    float s = 0.f;
    for (int m = threadIdx.x; m < M; m += blockDim.x)
        s += logf(S[m]) - goldv[m];
#pragma unroll
    for (int d = 1; d < 64; d <<= 1) s += __shfl_xor(s, d);
    __shared__ float wsum[4];
    const int wid = threadIdx.x >> 6, lane = threadIdx.x & 63;
    if (lane == 0) wsum[wid] = s;
    __syncthreads();
    if (threadIdx.x == 0)
        out[0] = (wsum[0] + wsum[1] + wsum[2] + wsum[3]) / fhdr[0];
}

extern "C" void kernel_launch(void* const* d_in, const int* in_sizes, int n_in,
                              void* d_out, int out_size, void* d_ws, size_t ws_size,
                              hipStream_t stream) {
    const float* hs  = (const float*)d_in[0];
    const float* W   = (const float*)d_in[1];
    const float* fb  = (const float*)d_in[2];
    const float* bb  = (const float*)d_in[3];
    const int* sent  = (const int*)d_in[4];
    const int* bs    = (const int*)d_in[5];
    const int total  = in_sizes[4];
    const int T      = in_sizes[5];
    const int V      = in_sizes[2];
    const int D      = in_sizes[1] / V;
    const int D2     = in_sizes[0] / total;
    const int Mcap   = ((2 * total) + 127) & ~127;   // 128-aligned upper bound
    const int MT     = Mcap / 128;
    const int NN     = V / 256;

    char* p = (char*)d_ws;
    int*   hdr     = (int*)p;            p += 256;
    float* fhdr    = (float*)p;          p += 256;
    int*   row_ctx = (int*)p;            p += (size_t)Mcap * 4;
    int*   row_tok = (int*)p;            p += (size_t)Mcap * 4;
    float* S       = (float*)p;          p += (size_t)Mcap * 4;
    float* goldv   = (float*)p;          p += (size_t)Mcap * 4;
    uint8_t* Hc    = (uint8_t*)p;        p += (size_t)Mcap * D;     // fp8
    uint8_t* Wb    = (uint8_t*)p;
    const size_t need_wb = (size_t)(p - (char*)d_ws) + (size_t)V * D;

    prep_kernel<<<1, 256, 0, stream>>>(bs, T, sent, hdr, fhdr, row_ctx, row_tok);

    if (ws_size >= need_wb) {
        gather_kernel<<<MT * 8, 512, 0, stream>>>(hs, row_ctx, hdr, Hc, S, D2, D);
        wconv_kernel<<<(V / 256) * 16, 512, 0, stream>>>(W, Wb, D);
        gemm_lse<<<NN * MT, 512, 0, stream>>>(Hc, Wb, fb, bb, S, hdr, D, MT);
    } else {
        lse_naive<<<Mcap, 256, 0, stream>>>(hs, W, fb, bb, row_ctx, hdr, S, D2, D, V);
    }

    gold_kernel<<<Mcap, 256, 0, stream>>>(hs, W, fb, bb, row_ctx, row_tok, hdr, goldv, D2, D);
    final_kernel<<<1, 256, 0, stream>>>(S, goldv, hdr, fhdr, (float*)d_out);
}